// Round 1
// baseline (112.502 us; speedup 1.0000x reference)
//
#include <hip/hip_runtime.h>

// FK_Velocity_Loss: pos_loss = vel_loss = mean((out_fk - gt_fk)^2)
// (gt_prev_pose cancels exactly: (o - p) - (g - p) = o - g)
// Traffic: only output_pose + gt_pose = 409.6 MB read. Memory-bound, target ~65us.

#define N_ROWS 400000
#define N_CHAINS (N_ROWS * 2)
#define MEAN_DIV ((double)(N_ROWS) * 2.0 * 3.0)

__global__ void fk_zero_acc(double* acc) { acc[0] = 0.0; }

// Compute translation column of M0*M1*M2*M3 via right-to-left mat-vec:
// v = M3[:,3]; v = M2*v; v = M1*v; v = M0*v.  Matrices are row-major 4x4,
// chain = 64 contiguous floats (4 matrices of 16).
__device__ __forceinline__ void fk_chain3(const float4* __restrict__ p,
                                          float& x, float& y, float& z) {
    float4 q[16];
#pragma unroll
    for (int i = 0; i < 16; ++i) q[i] = p[i];
    // M3 column 3:
    float v0 = q[12].w, v1 = q[13].w, v2 = q[14].w, v3 = q[15].w;
#pragma unroll
    for (int j = 2; j >= 0; --j) {
        float4 r0 = q[j * 4 + 0], r1 = q[j * 4 + 1];
        float4 r2 = q[j * 4 + 2], r3 = q[j * 4 + 3];
        float n0 = r0.x * v0 + r0.y * v1 + r0.z * v2 + r0.w * v3;
        float n1 = r1.x * v0 + r1.y * v1 + r1.z * v2 + r1.w * v3;
        float n2 = r2.x * v0 + r2.y * v1 + r2.z * v2 + r2.w * v3;
        float n3 = r3.x * v0 + r3.y * v1 + r3.z * v2 + r3.w * v3;
        v0 = n0; v1 = n1; v2 = n2; v3 = n3;
    }
    x = v0; y = v1; z = v2;
}

__global__ __launch_bounds__(256) void fk_loss_kernel(const float* __restrict__ outp,
                                                      const float* __restrict__ gtp,
                                                      double* __restrict__ acc) {
    const int tid = blockIdx.x * blockDim.x + threadIdx.x;  // one thread per chain
    float ss = 0.0f;
    if (tid < N_CHAINS) {
        const float4* po = reinterpret_cast<const float4*>(outp) + (size_t)tid * 16;
        const float4* pg = reinterpret_cast<const float4*>(gtp) + (size_t)tid * 16;
        float ox, oy, oz, gx, gy, gz;
        fk_chain3(po, ox, oy, oz);
        fk_chain3(pg, gx, gy, gz);
        float dx = ox - gx, dy = oy - gy, dz = oz - gz;
        ss = dx * dx + dy * dy + dz * dz;
    }
    // wave64 shuffle reduce
#pragma unroll
    for (int off = 32; off > 0; off >>= 1) ss += __shfl_down(ss, off, 64);
    __shared__ float part[4];
    const int wave = threadIdx.x >> 6;
    const int lane = threadIdx.x & 63;
    if (lane == 0) part[wave] = ss;
    __syncthreads();
    if (threadIdx.x == 0) {
        float b = part[0] + part[1] + part[2] + part[3];
        atomicAdd(acc, (double)b);  // device-scope f64 atomic, one per block
    }
}

__global__ void fk_finalize(const double* __restrict__ acc, float* __restrict__ out) {
    float v = (float)(acc[0] / MEAN_DIV);
    out[0] = v;  // pos_loss
    out[1] = v;  // vel_loss (identical: gt_prev cancels)
}

extern "C" void kernel_launch(void* const* d_in, const int* in_sizes, int n_in,
                              void* d_out, int out_size, void* d_ws, size_t ws_size,
                              hipStream_t stream) {
    const float* output_pose = (const float*)d_in[0];
    const float* gt_pose     = (const float*)d_in[1];
    // d_in[2] (gt_prev_pose) and d_in[3] (gt_pos) are not needed.
    float* out = (float*)d_out;
    double* acc = (double*)d_ws;

    fk_zero_acc<<<1, 1, 0, stream>>>(acc);
    const int threads = 256;
    const int blocks = (N_CHAINS + threads - 1) / threads;  // 3125
    fk_loss_kernel<<<blocks, threads, 0, stream>>>(output_pose, gt_pose, acc);
    fk_finalize<<<1, 1, 0, stream>>>(acc, out);
}

// Round 2
// 82.385 us; speedup vs baseline: 1.3656x; 1.3656x over previous
//
#include <hip/hip_runtime.h>

// FK_Velocity_Loss: pos_loss = vel_loss = mean((out_fk - gt_fk)^2)
// (gt_prev_pose cancels exactly: (o - p) - (g - p) = o - g)
//
// R2: 4 lanes per chain. Lane k of each quad holds ROW k of each 4x4 matrix,
// so a quad's loads are 4 consecutive float4s = one fully-covered 64B sector
// per quad per instruction (vs 64 quarter-line requests/instr in R1).
// Mat-vec chain v <- Mj*v uses DPP quad_perm broadcasts (VALU-only).

#define N_ROWS 400000
#define N_CHAINS (N_ROWS * 2)            // 800000 chains
#define ITERS 4
#define THREADS_TOTAL (N_CHAINS * 4 / ITERS)  // 800000 threads
#define BLOCK 256
#define BLOCKS (THREADS_TOTAL / BLOCK)        // 3125, exact
#define CHAIN_STRIDE (N_CHAINS / ITERS)       // 200000 chains per iteration
#define MEAN_DIV ((double)(N_ROWS) * 2.0 * 3.0)

__global__ void fk_zero_acc(double* acc) { acc[0] = 0.0; }

// Broadcast lane (quad_base + I)'s value across the quad. DPP quad_perm.
template <int I>
__device__ __forceinline__ float qb(float x) {
    return __builtin_bit_cast(float,
        __builtin_amdgcn_mov_dpp(__builtin_bit_cast(int, x),
                                 I | (I << 2) | (I << 4) | (I << 6),
                                 0xF, 0xF, true));
}

// This lane holds row k of M0..M3 (m0..m3). Returns component k of
// (M0*M1*M2*M3)[:,3] computed right-to-left: v=M3[:,3]; v=M2*v; v=M1*v; v=M0*v.
__device__ __forceinline__ float fk_elem(float4 m0, float4 m1, float4 m2, float4 m3) {
    float v = m3.w;  // lane k holds col-3 element k of M3
    float v0, v1, v2, v3;
    v0 = qb<0>(v); v1 = qb<1>(v); v2 = qb<2>(v); v3 = qb<3>(v);
    v = m2.x * v0 + m2.y * v1 + m2.z * v2 + m2.w * v3;
    v0 = qb<0>(v); v1 = qb<1>(v); v2 = qb<2>(v); v3 = qb<3>(v);
    v = m1.x * v0 + m1.y * v1 + m1.z * v2 + m1.w * v3;
    v0 = qb<0>(v); v1 = qb<1>(v); v2 = qb<2>(v); v3 = qb<3>(v);
    v = m0.x * v0 + m0.y * v1 + m0.z * v2 + m0.w * v3;
    return v;
}

__global__ __launch_bounds__(BLOCK) void fk_loss_kernel(const float* __restrict__ outp,
                                                        const float* __restrict__ gtp,
                                                        double* __restrict__ acc) {
    const int tid = blockIdx.x * BLOCK + threadIdx.x;
    const int k = tid & 3;  // row index within quad (== lane&3, BLOCK%4==0)
    float ss = 0.0f;
#pragma unroll
    for (int it = 0; it < ITERS; ++it) {
        const int c = (tid >> 2) + it * CHAIN_STRIDE;  // chain index, no tail
        const float4* po = reinterpret_cast<const float4*>(outp) + (size_t)c * 16 + k;
        const float4* pg = reinterpret_cast<const float4*>(gtp) + (size_t)c * 16 + k;
        float4 o0 = po[0], o1 = po[4], o2 = po[8], o3 = po[12];
        float4 g0 = pg[0], g1 = pg[4], g2 = pg[8], g3 = pg[12];
        float fo = fk_elem(o0, o1, o2, o3);
        float fg = fk_elem(g0, g1, g2, g3);
        float d = fo - fg;
        ss += (k < 3) ? d * d : 0.0f;  // row-3 output excluded (operand still needed)
    }
    // wave64 shuffle reduce
#pragma unroll
    for (int off = 32; off > 0; off >>= 1) ss += __shfl_down(ss, off, 64);
    __shared__ float part[BLOCK / 64];
    const int wave = threadIdx.x >> 6;
    const int lane = threadIdx.x & 63;
    if (lane == 0) part[wave] = ss;
    __syncthreads();
    if (threadIdx.x == 0) {
        float b = part[0] + part[1] + part[2] + part[3];
        atomicAdd(acc, (double)b);  // one device-scope f64 atomic per block
    }
}

__global__ void fk_finalize(const double* __restrict__ acc, float* __restrict__ out) {
    float v = (float)(acc[0] / MEAN_DIV);
    out[0] = v;  // pos_loss
    out[1] = v;  // vel_loss (identical: gt_prev cancels)
}

extern "C" void kernel_launch(void* const* d_in, const int* in_sizes, int n_in,
                              void* d_out, int out_size, void* d_ws, size_t ws_size,
                              hipStream_t stream) {
    const float* output_pose = (const float*)d_in[0];
    const float* gt_pose     = (const float*)d_in[1];
    // d_in[2] (gt_prev_pose) and d_in[3] (gt_pos) are not needed.
    float* out = (float*)d_out;
    double* acc = (double*)d_ws;

    fk_zero_acc<<<1, 1, 0, stream>>>(acc);
    fk_loss_kernel<<<BLOCKS, BLOCK, 0, stream>>>(output_pose, gt_pose, acc);
    fk_finalize<<<1, 1, 0, stream>>>(acc, out);
}